// Round 5
// baseline (72.728 us; speedup 1.0000x reference)
//
#include <hip/hip_runtime.h>

// ROI Align forward, fp32. Fixed shapes:
//   input: (N=4, C=256, H=200, W=200) f32
//   rois:  (M=1024, 5) f32   [batch_idx, x1, y1, x2, y2]
//   out:   (M, C, 7, 7) f32
//
// Paired-corner design:
//   - corners (y,x0)/(y,x0+1) are adjacent -> one 8B load per row, 2 loads
//     per output instead of 4. Clamp cases folded into precomputed weights:
//     pair start xs = clamp(x0,0,W-2); weight goes to .x or .y lane by sel.
//   - lane = bin position (0..48), wave walks channels; offsets+weights
//     hoisted to registers from LDS once.
//   - unroll 8 -> 16 paired loads in flight per lane.
//   - XCD swizzle: both SPLITC blocks of a ROI land on the same XCD so the
//     ROI footprint is cached in ONE L2 instead of two.

#define OUT_H 7
#define OUT_W 7
#define NPOS 49
#define SPATIAL_SCALE 0.25f
#define BLOCK 256
#define C_CONST 256
#define H_CONST 200
#define W_CONST 200
#define HW_CONST (H_CONST * W_CONST)
#define SPLITC 2                              // blocks per ROI
#define CH_PER_WAVE (C_CONST / SPLITC / 4)    // 32 channels per wave

__global__ __launch_bounds__(BLOCK) void roi_align_fwd(
        const float* __restrict__ inp,
        const float* __restrict__ rois,
        float* __restrict__ out) {
    // XCD-aware remap: hardware round-robins blockIdx across 8 XCDs.
    // Map so ROI m's SPLITC blocks share one XCD (m % 8 == xcd).
    const int bid = blockIdx.x;
    const int xcd = bid & 7;
    const int j   = bid >> 3;                  // 0 .. M*SPLITC/8-1
    const int m   = xcd + 8 * (j / SPLITC);
    const int seg = j % SPLITC;

    __shared__ int2   s_off[NPOS];   // {offTop, offBot} element offsets (incl. b*C*HW)
    __shared__ float4 s_w[NPOS];     // folded weights {WT0, WT1, WB0, WB1}

    const float* __restrict__ r = rois + (size_t)m * 5;

    if (threadIdx.x < NPOS) {
        const int pos = threadIdx.x;
        const int ph = pos / OUT_W;
        const int pw = pos % OUT_W;

        const int   b  = (int)r[0];
        const float x1 = r[1] * SPATIAL_SCALE;
        const float y1 = r[2] * SPATIAL_SCALE;
        const float x2 = r[3] * SPATIAL_SCALE;
        const float y2 = r[4] * SPATIAL_SCALE;

        const float roi_w = fmaxf(x2 - x1, 1.0f);
        const float roi_h = fmaxf(y2 - y1, 1.0f);
        const float bin_w = roi_w * (1.0f / OUT_W);
        const float bin_h = roi_h * (1.0f / OUT_H);

        const float y_s = y1 + ((float)ph + 0.5f) * bin_h;
        const float x_s = x1 + ((float)pw + 0.5f) * bin_w;
        const float py  = y_s * ((float)(H_CONST - 1) / (float)H_CONST);
        const float px  = x_s * ((float)(W_CONST - 1) / (float)W_CONST);

        const float fy = floorf(py);
        const float fx = floorf(px);
        const int y0 = (int)fy;
        const int x0 = (int)fx;
        const float ly = py - fy;
        const float lx = px - fx;

        const int y1i = y0 + 1;
        const int x1i = x0 + 1;

        const bool vy0 = (y0  >= 0) & (y0  < H_CONST);
        const bool vy1 = (y1i >= 0) & (y1i < H_CONST);
        const bool vx0 = (x0  >= 0) & (x0  < W_CONST);
        const bool vx1 = (x1i >= 0) & (x1i < W_CONST);

        const int y0c = min(max(y0,  0), H_CONST - 1);
        const int y1c = min(max(y1i, 0), H_CONST - 1);
        const int x0c = min(max(x0,  0), W_CONST - 1);
        const int x1c = min(max(x1i, 0), W_CONST - 1);

        float w00 = (1.0f - ly) * (1.0f - lx);
        float w01 = (1.0f - ly) * lx;
        float w10 = ly * (1.0f - lx);
        float w11 = ly * lx;
        w00 = (vy0 & vx0) ? w00 : 0.0f;
        w01 = (vy0 & vx1) ? w01 : 0.0f;
        w10 = (vy1 & vx0) ? w10 : 0.0f;
        w11 = (vy1 & vx1) ? w11 : 0.0f;

        // Pair start & selection folding (x0c,x1c ∈ {xs, xs+1} always)
        const int xs   = min(max(x0, 0), W_CONST - 2);
        const int sel0 = x0c - xs;     // 0 or 1
        const int sel1 = x1c - xs;     // 0 or 1
        const float WT0 = (sel0 == 0 ? w00 : 0.0f) + (sel1 == 0 ? w01 : 0.0f);
        const float WT1 = (sel0 == 1 ? w00 : 0.0f) + (sel1 == 1 ? w01 : 0.0f);
        const float WB0 = (sel0 == 0 ? w10 : 0.0f) + (sel1 == 0 ? w11 : 0.0f);
        const float WB1 = (sel0 == 1 ? w10 : 0.0f) + (sel1 == 1 ? w11 : 0.0f);

        const int nb = b * (C_CONST * HW_CONST);
        s_off[pos] = make_int2(nb + y0c * W_CONST + xs,
                               nb + y1c * W_CONST + xs);
        s_w[pos]   = make_float4(WT0, WT1, WB0, WB1);
    }
    __syncthreads();

    const int lane = threadIdx.x & 63;
    const int wid  = threadIdx.x >> 6;          // 0..3

    if (lane < NPOS) {
        const int pos = lane;
        const int2   off = s_off[pos];
        const float4 w   = s_w[pos];
        const int c0 = seg * (C_CONST / SPLITC) + wid;   // wave's first channel

        const float* pT = inp + (size_t)(unsigned)(off.x + c0 * HW_CONST);
        const float* pB = inp + (size_t)(unsigned)(off.y + c0 * HW_CONST);

        float* po = out + (size_t)m * (C_CONST * NPOS)
                        + (size_t)c0 * NPOS + pos;

        const int cstep = 4 * HW_CONST;   // 4 channels per iteration (per wave)
#pragma unroll 8
        for (int k = 0; k < CH_PER_WAVE; ++k) {
            float2 vT, vB;
            __builtin_memcpy(&vT, pT, 8);   // align-4 safe 8B pair load
            __builtin_memcpy(&vB, pB, 8);
            *po = w.x * vT.x + w.y * vT.y + w.z * vB.x + w.w * vB.y;
            pT += cstep; pB += cstep;
            po += 4 * NPOS;
        }
    }
}

extern "C" void kernel_launch(void* const* d_in, const int* in_sizes, int n_in,
                              void* d_out, int out_size, void* d_ws, size_t ws_size,
                              hipStream_t stream) {
    const float* inp  = (const float*)d_in[0];
    const float* rois = (const float*)d_in[1];
    float* out = (float*)d_out;

    const int M = in_sizes[1] / 5;            // 1024
    const int grid = M * SPLITC;              // 2048 blocks = 32 waves/CU

    roi_align_fwd<<<grid, BLOCK, 0, stream>>>(inp, rois, out);
}

// Round 6
// 48.798 us; speedup vs baseline: 1.4904x; 1.4904x over previous
//
#include <hip/hip_runtime.h>

// ROI Align forward, fp32. Fixed shapes:
//   input: (N=4, C=256, H=200, W=200) f32   (164 MB)
//   rois:  (M=1024, 5) f32   [batch_idx, x1, y1, x2, y2]
//   out:   (M, C, 7, 7) f32                 (51 MB)
//
// Two-phase, L2-locality-scheduled design:
//   Phase 1 (precompute): per (m,pos) -> paired-corner offsets (top/bottom
//     row pair start, b*C*HW folded in) + validity/clamp-folded 4 weights.
//     1.2 MB table in d_ws; stays L2-resident.
//   Phase 2 (gather): grid mapped so XCD = blockIdx%8 owns a fixed 32-channel
//     slice; roi-group is the fastest-varying slot index, so concurrent
//     blocks on an XCD share a ~2.5 MB input window (CPB=4 channels x 4
//     batch planes) that FITS the 4 MB XCD-L2. Each input line is fetched
//     from HBM by exactly one XCD, once; gathers hit L2.

#define OUT_H 7
#define OUT_W 7
#define NPOS 49
#define SPATIAL_SCALE 0.25f
#define C_CONST 256
#define H_CONST 200
#define W_CONST 200
#define HW_CONST (H_CONST * W_CONST)
#define M_CONST 1024
#define CPB 4                    // channels per block (phase 2)
#define RPB 16                   // ROIs per block (phase 2)
#define TAB_OFF_BYTES ((size_t)M_CONST * NPOS * sizeof(int2))     // 401,408
#define TAB_BYTES (TAB_OFF_BYTES + (size_t)M_CONST * NPOS * sizeof(float4))

__global__ __launch_bounds__(256) void roi_precompute(
        const float* __restrict__ rois,
        int2*   __restrict__ toff,
        float4* __restrict__ tw) {
    const int idx = blockIdx.x * blockDim.x + threadIdx.x;
    if (idx >= M_CONST * NPOS) return;
    const int m   = idx / NPOS;
    const int pos = idx - m * NPOS;
    const int ph = pos / OUT_W;
    const int pw = pos % OUT_W;

    const float* __restrict__ r = rois + (size_t)m * 5;
    const int   b  = (int)r[0];
    const float x1 = r[1] * SPATIAL_SCALE;
    const float y1 = r[2] * SPATIAL_SCALE;
    const float x2 = r[3] * SPATIAL_SCALE;
    const float y2 = r[4] * SPATIAL_SCALE;

    const float roi_w = fmaxf(x2 - x1, 1.0f);
    const float roi_h = fmaxf(y2 - y1, 1.0f);
    const float bin_w = roi_w * (1.0f / OUT_W);
    const float bin_h = roi_h * (1.0f / OUT_H);

    const float y_s = y1 + ((float)ph + 0.5f) * bin_h;
    const float x_s = x1 + ((float)pw + 0.5f) * bin_w;
    const float py  = y_s * ((float)(H_CONST - 1) / (float)H_CONST);
    const float px  = x_s * ((float)(W_CONST - 1) / (float)W_CONST);

    const float fy = floorf(py);
    const float fx = floorf(px);
    const int y0 = (int)fy;
    const int x0 = (int)fx;
    const float ly = py - fy;
    const float lx = px - fx;

    const int y1i = y0 + 1;
    const int x1i = x0 + 1;

    const bool vy0 = (y0  >= 0) & (y0  < H_CONST);
    const bool vy1 = (y1i >= 0) & (y1i < H_CONST);
    const bool vx0 = (x0  >= 0) & (x0  < W_CONST);
    const bool vx1 = (x1i >= 0) & (x1i < W_CONST);

    const int y0c = min(max(y0,  0), H_CONST - 1);
    const int y1c = min(max(y1i, 0), H_CONST - 1);
    const int x0c = min(max(x0,  0), W_CONST - 1);
    const int x1c = min(max(x1i, 0), W_CONST - 1);

    float w00 = (1.0f - ly) * (1.0f - lx);
    float w01 = (1.0f - ly) * lx;
    float w10 = ly * (1.0f - lx);
    float w11 = ly * lx;
    w00 = (vy0 & vx0) ? w00 : 0.0f;
    w01 = (vy0 & vx1) ? w01 : 0.0f;
    w10 = (vy1 & vx0) ? w10 : 0.0f;
    w11 = (vy1 & vx1) ? w11 : 0.0f;

    // pair start + selection folding (x0c, x1c always ∈ {xs, xs+1})
    const int xs   = min(max(x0, 0), W_CONST - 2);
    const int sel0 = x0c - xs;
    const int sel1 = x1c - xs;
    const float WT0 = (sel0 == 0 ? w00 : 0.0f) + (sel1 == 0 ? w01 : 0.0f);
    const float WT1 = (sel0 == 1 ? w00 : 0.0f) + (sel1 == 1 ? w01 : 0.0f);
    const float WB0 = (sel0 == 0 ? w10 : 0.0f) + (sel1 == 0 ? w11 : 0.0f);
    const float WB1 = (sel0 == 1 ? w10 : 0.0f) + (sel1 == 1 ? w11 : 0.0f);

    const int nb = b * (C_CONST * HW_CONST);
    toff[idx] = make_int2(nb + y0c * W_CONST + xs,
                          nb + y1c * W_CONST + xs);
    tw[idx]   = make_float4(WT0, WT1, WB0, WB1);
}

// Phase 2: grid = 8 XCDs x 8 c-groups x 64 roi-groups = 4096 blocks.
// blockIdx%8 = XCD (hardware round-robin); slot = blockIdx/8;
// c-group = slot/64 (slow), roi-group = slot%64 (fast) -> concurrent blocks
// on an XCD share one CPB-channel window (~2.5 MB, L2-resident).
__global__ __launch_bounds__(256) void roi_gather(
        const float* __restrict__ inp,
        const int2*   __restrict__ toff,
        const float4* __restrict__ tw,
        float* __restrict__ out) {
    const int B   = blockIdx.x;
    const int xcd = B & 7;
    const int s   = B >> 3;            // 0..511
    const int cg  = s >> 6;            // 0..7  (slow)
    const int rg  = s & 63;            // 0..63 (fast)
    const int c0  = (xcd * 8 + cg) * CPB;   // this XCD owns channels [xcd*32, xcd*32+32)
    const int m0  = rg * RPB;

    const int lane = threadIdx.x & 63;
    const int wid  = threadIdx.x >> 6;      // 0..3, each wave: 4 ROIs
    if (lane >= NPOS) return;

    const int mbase = m0 + wid * 4;

#pragma unroll
    for (int i = 0; i < 4; ++i) {
        const int m = mbase + i;
        const int t = m * NPOS + lane;
        const int2   off = toff[t];
        const float4 w   = tw[t];

        const float* pT = inp + (size_t)(unsigned)off.x + (size_t)c0 * HW_CONST;
        const float* pB = inp + (size_t)(unsigned)off.y + (size_t)c0 * HW_CONST;
        float* po = out + ((size_t)m * C_CONST + c0) * NPOS + lane;

#pragma unroll
        for (int c = 0; c < CPB; ++c) {
            float2 vT, vB;
            __builtin_memcpy(&vT, pT + (size_t)c * HW_CONST, 8);
            __builtin_memcpy(&vB, pB + (size_t)c * HW_CONST, 8);
            po[c * NPOS] = w.x * vT.x + w.y * vT.y + w.z * vB.x + w.w * vB.y;
        }
    }
}

// Fallback (ws too small): round-3-style position-resident single kernel.
__global__ __launch_bounds__(256) void roi_align_fallback(
        const float* __restrict__ inp,
        const float* __restrict__ rois,
        float* __restrict__ out) {
    const int m   = blockIdx.x >> 1;
    const int seg = blockIdx.x & 1;

    __shared__ int2   s_off[NPOS];
    __shared__ float4 s_w[NPOS];

    const float* __restrict__ r = rois + (size_t)m * 5;

    if (threadIdx.x < NPOS) {
        const int pos = threadIdx.x;
        const int ph = pos / OUT_W;
        const int pw = pos % OUT_W;
        const int   b  = (int)r[0];
        const float x1 = r[1] * SPATIAL_SCALE;
        const float y1 = r[2] * SPATIAL_SCALE;
        const float x2 = r[3] * SPATIAL_SCALE;
        const float y2 = r[4] * SPATIAL_SCALE;
        const float roi_w = fmaxf(x2 - x1, 1.0f);
        const float roi_h = fmaxf(y2 - y1, 1.0f);
        const float bin_w = roi_w * (1.0f / OUT_W);
        const float bin_h = roi_h * (1.0f / OUT_H);
        const float y_s = y1 + ((float)ph + 0.5f) * bin_h;
        const float x_s = x1 + ((float)pw + 0.5f) * bin_w;
        const float py  = y_s * ((float)(H_CONST - 1) / (float)H_CONST);
        const float px  = x_s * ((float)(W_CONST - 1) / (float)W_CONST);
        const float fy = floorf(py);
        const float fx = floorf(px);
        const int y0 = (int)fy;
        const int x0 = (int)fx;
        const float ly = py - fy;
        const float lx = px - fx;
        const int y1i = y0 + 1, x1i = x0 + 1;
        const bool vy0 = (y0  >= 0) & (y0  < H_CONST);
        const bool vy1 = (y1i >= 0) & (y1i < H_CONST);
        const bool vx0 = (x0  >= 0) & (x0  < W_CONST);
        const bool vx1 = (x1i >= 0) & (x1i < W_CONST);
        const int y0c = min(max(y0,  0), H_CONST - 1);
        const int y1c = min(max(y1i, 0), H_CONST - 1);
        const int x0c = min(max(x0,  0), W_CONST - 1);
        const int x1c = min(max(x1i, 0), W_CONST - 1);
        float w00 = (1.0f - ly) * (1.0f - lx);
        float w01 = (1.0f - ly) * lx;
        float w10 = ly * (1.0f - lx);
        float w11 = ly * lx;
        w00 = (vy0 & vx0) ? w00 : 0.0f;
        w01 = (vy0 & vx1) ? w01 : 0.0f;
        w10 = (vy1 & vx0) ? w10 : 0.0f;
        w11 = (vy1 & vx1) ? w11 : 0.0f;
        const int xs   = min(max(x0, 0), W_CONST - 2);
        const int sel0 = x0c - xs;
        const int sel1 = x1c - xs;
        const float WT0 = (sel0 == 0 ? w00 : 0.0f) + (sel1 == 0 ? w01 : 0.0f);
        const float WT1 = (sel0 == 1 ? w00 : 0.0f) + (sel1 == 1 ? w01 : 0.0f);
        const float WB0 = (sel0 == 0 ? w10 : 0.0f) + (sel1 == 0 ? w11 : 0.0f);
        const float WB1 = (sel0 == 1 ? w10 : 0.0f) + (sel1 == 1 ? w11 : 0.0f);
        const int nb = b * (C_CONST * HW_CONST);
        s_off[pos] = make_int2(nb + y0c * W_CONST + xs, nb + y1c * W_CONST + xs);
        s_w[pos]   = make_float4(WT0, WT1, WB0, WB1);
    }
    __syncthreads();

    const int lane = threadIdx.x & 63;
    const int wid  = threadIdx.x >> 6;
    if (lane < NPOS) {
        const int2   off = s_off[lane];
        const float4 w   = s_w[lane];
        const int c0 = seg * (C_CONST / 2) + wid;
        const float* pT = inp + (size_t)(unsigned)(off.x + c0 * HW_CONST);
        const float* pB = inp + (size_t)(unsigned)(off.y + c0 * HW_CONST);
        float* po = out + (size_t)m * (C_CONST * NPOS) + (size_t)c0 * NPOS + lane;
        const int cstep = 4 * HW_CONST;
#pragma unroll 8
        for (int k = 0; k < C_CONST / 2 / 4; ++k) {
            float2 vT, vB;
            __builtin_memcpy(&vT, pT, 8);
            __builtin_memcpy(&vB, pB, 8);
            *po = w.x * vT.x + w.y * vT.y + w.z * vB.x + w.w * vB.y;
            pT += cstep; pB += cstep;
            po += 4 * NPOS;
        }
    }
}

extern "C" void kernel_launch(void* const* d_in, const int* in_sizes, int n_in,
                              void* d_out, int out_size, void* d_ws, size_t ws_size,
                              hipStream_t stream) {
    const float* inp  = (const float*)d_in[0];
    const float* rois = (const float*)d_in[1];
    float* out = (float*)d_out;

    if (ws_size >= TAB_BYTES) {
        int2*   toff = (int2*)d_ws;
        float4* tw   = (float4*)((char*)d_ws + TAB_OFF_BYTES);

        const int total1 = M_CONST * NPOS;                 // 50176
        roi_precompute<<<(total1 + 255) / 256, 256, 0, stream>>>(rois, toff, tw);

        const int grid2 = 8 * 8 * 64;                      // 4096 blocks
        roi_gather<<<grid2, 256, 0, stream>>>(inp, toff, tw, out);
    } else {
        const int M = in_sizes[1] / 5;
        roi_align_fallback<<<M * 2, 256, 0, stream>>>(inp, rois, out);
    }
}

// Round 7
// 48.530 us; speedup vs baseline: 1.4986x; 1.0055x over previous
//
#include <hip/hip_runtime.h>

// ROI Align forward, fp32. Fixed shapes:
//   input: (N=4, C=256, H=200, W=200) f32   (164 MB)
//   rois:  (M=1024, 5) f32   [batch_idx, x1, y1, x2, y2]
//   out:   (M, C, 7, 7) f32                 (51 MB)
//
// Two-phase, L2-locality-scheduled design (round 6) + deep MLP (round 7):
//   Phase 1: per (m,pos) paired-corner offsets + folded weights -> d_ws.
//   Phase 2: XCD = blockIdx%8 owns a 32-channel slice; roi-group varies
//     fastest so concurrent blocks on an XCD share a ~2.5 MB input window
//     (L2-resident). NEW: inner body is load-all-then-compute-all — 8 table
//     loads + 32 paired loads issued back-to-back into registers (static
//     indexing, stays in VGPRs) before any FMA/store. ~40 loads in flight
//     per lane to cover L2/HBM latency.

#define OUT_H 7
#define OUT_W 7
#define NPOS 49
#define SPATIAL_SCALE 0.25f
#define C_CONST 256
#define H_CONST 200
#define W_CONST 200
#define HW_CONST (H_CONST * W_CONST)
#define M_CONST 1024
#define CPB 4                    // channels per block (phase 2)
#define RPB 16                   // ROIs per block (phase 2)
#define TAB_OFF_BYTES ((size_t)M_CONST * NPOS * sizeof(int2))     // 401,408
#define TAB_BYTES (TAB_OFF_BYTES + (size_t)M_CONST * NPOS * sizeof(float4))

__global__ __launch_bounds__(256) void roi_precompute(
        const float* __restrict__ rois,
        int2*   __restrict__ toff,
        float4* __restrict__ tw) {
    const int idx = blockIdx.x * blockDim.x + threadIdx.x;
    if (idx >= M_CONST * NPOS) return;
    const int m   = idx / NPOS;
    const int pos = idx - m * NPOS;
    const int ph = pos / OUT_W;
    const int pw = pos % OUT_W;

    const float* __restrict__ r = rois + (size_t)m * 5;
    const int   b  = (int)r[0];
    const float x1 = r[1] * SPATIAL_SCALE;
    const float y1 = r[2] * SPATIAL_SCALE;
    const float x2 = r[3] * SPATIAL_SCALE;
    const float y2 = r[4] * SPATIAL_SCALE;

    const float roi_w = fmaxf(x2 - x1, 1.0f);
    const float roi_h = fmaxf(y2 - y1, 1.0f);
    const float bin_w = roi_w * (1.0f / OUT_W);
    const float bin_h = roi_h * (1.0f / OUT_H);

    const float y_s = y1 + ((float)ph + 0.5f) * bin_h;
    const float x_s = x1 + ((float)pw + 0.5f) * bin_w;
    const float py  = y_s * ((float)(H_CONST - 1) / (float)H_CONST);
    const float px  = x_s * ((float)(W_CONST - 1) / (float)W_CONST);

    const float fy = floorf(py);
    const float fx = floorf(px);
    const int y0 = (int)fy;
    const int x0 = (int)fx;
    const float ly = py - fy;
    const float lx = px - fx;

    const int y1i = y0 + 1;
    const int x1i = x0 + 1;

    const bool vy0 = (y0  >= 0) & (y0  < H_CONST);
    const bool vy1 = (y1i >= 0) & (y1i < H_CONST);
    const bool vx0 = (x0  >= 0) & (x0  < W_CONST);
    const bool vx1 = (x1i >= 0) & (x1i < W_CONST);

    const int y0c = min(max(y0,  0), H_CONST - 1);
    const int y1c = min(max(y1i, 0), H_CONST - 1);
    const int x0c = min(max(x0,  0), W_CONST - 1);
    const int x1c = min(max(x1i, 0), W_CONST - 1);

    float w00 = (1.0f - ly) * (1.0f - lx);
    float w01 = (1.0f - ly) * lx;
    float w10 = ly * (1.0f - lx);
    float w11 = ly * lx;
    w00 = (vy0 & vx0) ? w00 : 0.0f;
    w01 = (vy0 & vx1) ? w01 : 0.0f;
    w10 = (vy1 & vx0) ? w10 : 0.0f;
    w11 = (vy1 & vx1) ? w11 : 0.0f;

    // pair start + selection folding (x0c, x1c always ∈ {xs, xs+1})
    const int xs   = min(max(x0, 0), W_CONST - 2);
    const int sel0 = x0c - xs;
    const int sel1 = x1c - xs;
    const float WT0 = (sel0 == 0 ? w00 : 0.0f) + (sel1 == 0 ? w01 : 0.0f);
    const float WT1 = (sel0 == 1 ? w00 : 0.0f) + (sel1 == 1 ? w01 : 0.0f);
    const float WB0 = (sel0 == 0 ? w10 : 0.0f) + (sel1 == 0 ? w11 : 0.0f);
    const float WB1 = (sel0 == 1 ? w10 : 0.0f) + (sel1 == 1 ? w11 : 0.0f);

    const int nb = b * (C_CONST * HW_CONST);
    toff[idx] = make_int2(nb + y0c * W_CONST + xs,
                          nb + y1c * W_CONST + xs);
    tw[idx]   = make_float4(WT0, WT1, WB0, WB1);
}

// Phase 2: grid = 8 XCDs x 8 c-groups x 64 roi-groups = 4096 blocks.
__global__ __launch_bounds__(256) void roi_gather(
        const float* __restrict__ inp,
        const int2*   __restrict__ toff,
        const float4* __restrict__ tw,
        float* __restrict__ out) {
    const int B   = blockIdx.x;
    const int xcd = B & 7;
    const int s   = B >> 3;            // 0..511
    const int cg  = s >> 6;            // 0..7  (slow)
    const int rg  = s & 63;            // 0..63 (fast)
    const int c0  = (xcd * 8 + cg) * CPB;   // XCD owns channels [xcd*32, xcd*32+32)
    const int m0  = rg * RPB;

    const int lane = threadIdx.x & 63;
    const int wid  = threadIdx.x >> 6;      // 0..3, each wave: 4 ROIs
    if (lane >= NPOS) return;

    const int mbase = m0 + wid * 4;

    // ---- stage 1: hoist table entries (8 independent loads) ----
    int2   off[4];
    float4 w[4];
#pragma unroll
    for (int i = 0; i < 4; ++i) {
        const int t = (mbase + i) * NPOS + lane;
        off[i] = toff[t];
        w[i]   = tw[t];
    }

    // ---- stage 2: issue ALL 32 paired-corner loads before any use ----
    float2 vT[4][CPB], vB[4][CPB];
#pragma unroll
    for (int i = 0; i < 4; ++i) {
#pragma unroll
        for (int c = 0; c < CPB; ++c) {
            const int eT = off[i].x + (c0 + c) * HW_CONST;
            const int eB = off[i].y + (c0 + c) * HW_CONST;
            __builtin_memcpy(&vT[i][c], inp + (size_t)(unsigned)eT, 8);
            __builtin_memcpy(&vB[i][c], inp + (size_t)(unsigned)eB, 8);
        }
    }

    // ---- stage 3: compute + store ----
#pragma unroll
    for (int i = 0; i < 4; ++i) {
        float* po = out + ((size_t)(mbase + i) * C_CONST + c0) * NPOS + lane;
#pragma unroll
        for (int c = 0; c < CPB; ++c) {
            po[c * NPOS] = w[i].x * vT[i][c].x + w[i].y * vT[i][c].y
                         + w[i].z * vB[i][c].x + w[i].w * vB[i][c].y;
        }
    }
}

// Fallback (ws too small): round-4-style position-resident single kernel.
__global__ __launch_bounds__(256) void roi_align_fallback(
        const float* __restrict__ inp,
        const float* __restrict__ rois,
        float* __restrict__ out) {
    const int m   = blockIdx.x >> 1;
    const int seg = blockIdx.x & 1;

    __shared__ int2   s_off[NPOS];
    __shared__ float4 s_w[NPOS];

    const float* __restrict__ r = rois + (size_t)m * 5;

    if (threadIdx.x < NPOS) {
        const int pos = threadIdx.x;
        const int ph = pos / OUT_W;
        const int pw = pos % OUT_W;
        const int   b  = (int)r[0];
        const float x1 = r[1] * SPATIAL_SCALE;
        const float y1 = r[2] * SPATIAL_SCALE;
        const float x2 = r[3] * SPATIAL_SCALE;
        const float y2 = r[4] * SPATIAL_SCALE;
        const float roi_w = fmaxf(x2 - x1, 1.0f);
        const float roi_h = fmaxf(y2 - y1, 1.0f);
        const float bin_w = roi_w * (1.0f / OUT_W);
        const float bin_h = roi_h * (1.0f / OUT_H);
        const float y_s = y1 + ((float)ph + 0.5f) * bin_h;
        const float x_s = x1 + ((float)pw + 0.5f) * bin_w;
        const float py  = y_s * ((float)(H_CONST - 1) / (float)H_CONST);
        const float px  = x_s * ((float)(W_CONST - 1) / (float)W_CONST);
        const float fy = floorf(py);
        const float fx = floorf(px);
        const int y0 = (int)fy;
        const int x0 = (int)fx;
        const float ly = py - fy;
        const float lx = px - fx;
        const int y1i = y0 + 1, x1i = x0 + 1;
        const bool vy0 = (y0  >= 0) & (y0  < H_CONST);
        const bool vy1 = (y1i >= 0) & (y1i < H_CONST);
        const bool vx0 = (x0  >= 0) & (x0  < W_CONST);
        const bool vx1 = (x1i >= 0) & (x1i < W_CONST);
        const int y0c = min(max(y0,  0), H_CONST - 1);
        const int y1c = min(max(y1i, 0), H_CONST - 1);
        const int x0c = min(max(x0,  0), W_CONST - 1);
        const int x1c = min(max(x1i, 0), W_CONST - 1);
        float w00 = (1.0f - ly) * (1.0f - lx);
        float w01 = (1.0f - ly) * lx;
        float w10 = ly * (1.0f - lx);
        float w11 = ly * lx;
        w00 = (vy0 & vx0) ? w00 : 0.0f;
        w01 = (vy0 & vx1) ? w01 : 0.0f;
        w10 = (vy1 & vx0) ? w10 : 0.0f;
        w11 = (vy1 & vx1) ? w11 : 0.0f;
        const int xs   = min(max(x0, 0), W_CONST - 2);
        const int sel0 = x0c - xs;
        const int sel1 = x1c - xs;
        const float WT0 = (sel0 == 0 ? w00 : 0.0f) + (sel1 == 0 ? w01 : 0.0f);
        const float WT1 = (sel0 == 1 ? w00 : 0.0f) + (sel1 == 1 ? w01 : 0.0f);
        const float WB0 = (sel0 == 0 ? w10 : 0.0f) + (sel1 == 0 ? w11 : 0.0f);
        const float WB1 = (sel0 == 1 ? w10 : 0.0f) + (sel1 == 1 ? w11 : 0.0f);
        const int nb = b * (C_CONST * HW_CONST);
        s_off[pos] = make_int2(nb + y0c * W_CONST + xs, nb + y1c * W_CONST + xs);
        s_w[pos]   = make_float4(WT0, WT1, WB0, WB1);
    }
    __syncthreads();

    const int lane = threadIdx.x & 63;
    const int wid  = threadIdx.x >> 6;
    if (lane < NPOS) {
        const int2   off = s_off[lane];
        const float4 w   = s_w[lane];
        const int c0 = seg * (C_CONST / 2) + wid;
        const float* pT = inp + (size_t)(unsigned)(off.x + c0 * HW_CONST);
        const float* pB = inp + (size_t)(unsigned)(off.y + c0 * HW_CONST);
        float* po = out + (size_t)m * (C_CONST * NPOS) + (size_t)c0 * NPOS + lane;
        const int cstep = 4 * HW_CONST;
#pragma unroll 8
        for (int k = 0; k < C_CONST / 2 / 4; ++k) {
            float2 vT, vB;
            __builtin_memcpy(&vT, pT, 8);
            __builtin_memcpy(&vB, pB, 8);
            *po = w.x * vT.x + w.y * vT.y + w.z * vB.x + w.w * vB.y;
            pT += cstep; pB += cstep;
            po += 4 * NPOS;
        }
    }
}

extern "C" void kernel_launch(void* const* d_in, const int* in_sizes, int n_in,
                              void* d_out, int out_size, void* d_ws, size_t ws_size,
                              hipStream_t stream) {
    const float* inp  = (const float*)d_in[0];
    const float* rois = (const float*)d_in[1];
    float* out = (float*)d_out;

    if (ws_size >= TAB_BYTES) {
        int2*   toff = (int2*)d_ws;
        float4* tw   = (float4*)((char*)d_ws + TAB_OFF_BYTES);

        const int total1 = M_CONST * NPOS;                 // 50176
        roi_precompute<<<(total1 + 255) / 256, 256, 0, stream>>>(rois, toff, tw);

        const int grid2 = 8 * 8 * 64;                      // 4096 blocks
        roi_gather<<<grid2, 256, 0, stream>>>(inp, toff, tw, out);
    } else {
        const int M = in_sizes[1] / 5;
        roi_align_fallback<<<M * 2, 256, 0, stream>>>(inp, rois, out);
    }
}

// Round 8
// 38.301 us; speedup vs baseline: 1.8989x; 1.2671x over previous
//
#include <hip/hip_runtime.h>

// ROI Align forward, fp32. Fixed shapes:
//   input: (N=4, C=256, H=200, W=200) f32   (164 MB)
//   rois:  (M=1024, 5) f32   [batch_idx, x1, y1, x2, y2]
//   out:   (M, C, 7, 7) f32                 (51 MB)
//
// Fused single-kernel, L2-locality-scheduled design:
//   - grid = 8 XCDs x 8 c-groups x 64 roi-groups; XCD = blockIdx%8 owns a
//     32-channel slice; roi-group varies fastest so concurrent blocks on an
//     XCD share a ~2.5 MB input window (CPB=4 ch x 4 batch planes) that fits
//     the 4 MB XCD-L2. Each input line goes HBM->L2 ~once; gathers hit L2.
//   - per-block table (16 ROIs x 49 positions: paired-corner offsets +
//     validity/clamp-folded weights) computed IN-KERNEL into LDS (~19 KB).
//     Removes the separate precompute kernel, its launch gap, and the
//     64x-reread of the global table.
//   - gather: lane = bin position, wave walks 4 ROIs x 4 channels; one 8B
//     paired load per row (corners are adjacent floats), clamp folded into
//     weights.

#define OUT_H 7
#define OUT_W 7
#define NPOS 49
#define SPATIAL_SCALE 0.25f
#define C_CONST 256
#define H_CONST 200
#define W_CONST 200
#define HW_CONST (H_CONST * W_CONST)
#define M_CONST 1024
#define CPB 4                    // channels per block
#define RPB 16                   // ROIs per block

__device__ __forceinline__ void roi_entry(const float* __restrict__ r,
                                          int pos, int2& off, float4& w) {
    const int ph = pos / OUT_W;
    const int pw = pos - ph * OUT_W;

    const int   b  = (int)r[0];
    const float x1 = r[1] * SPATIAL_SCALE;
    const float y1 = r[2] * SPATIAL_SCALE;
    const float x2 = r[3] * SPATIAL_SCALE;
    const float y2 = r[4] * SPATIAL_SCALE;

    const float roi_w = fmaxf(x2 - x1, 1.0f);
    const float roi_h = fmaxf(y2 - y1, 1.0f);
    const float bin_w = roi_w * (1.0f / OUT_W);
    const float bin_h = roi_h * (1.0f / OUT_H);

    const float y_s = y1 + ((float)ph + 0.5f) * bin_h;
    const float x_s = x1 + ((float)pw + 0.5f) * bin_w;
    const float py  = y_s * ((float)(H_CONST - 1) / (float)H_CONST);
    const float px  = x_s * ((float)(W_CONST - 1) / (float)W_CONST);

    const float fy = floorf(py);
    const float fx = floorf(px);
    const int y0 = (int)fy;
    const int x0 = (int)fx;
    const float ly = py - fy;
    const float lx = px - fx;

    const int y1i = y0 + 1;
    const int x1i = x0 + 1;

    const bool vy0 = (y0  >= 0) & (y0  < H_CONST);
    const bool vy1 = (y1i >= 0) & (y1i < H_CONST);
    const bool vx0 = (x0  >= 0) & (x0  < W_CONST);
    const bool vx1 = (x1i >= 0) & (x1i < W_CONST);

    const int y0c = min(max(y0,  0), H_CONST - 1);
    const int y1c = min(max(y1i, 0), H_CONST - 1);
    const int x0c = min(max(x0,  0), W_CONST - 1);
    const int x1c = min(max(x1i, 0), W_CONST - 1);

    float w00 = (1.0f - ly) * (1.0f - lx);
    float w01 = (1.0f - ly) * lx;
    float w10 = ly * (1.0f - lx);
    float w11 = ly * lx;
    w00 = (vy0 & vx0) ? w00 : 0.0f;
    w01 = (vy0 & vx1) ? w01 : 0.0f;
    w10 = (vy1 & vx0) ? w10 : 0.0f;
    w11 = (vy1 & vx1) ? w11 : 0.0f;

    // pair start + selection folding (x0c, x1c always ∈ {xs, xs+1})
    const int xs   = min(max(x0, 0), W_CONST - 2);
    const int sel0 = x0c - xs;
    const int sel1 = x1c - xs;
    const float WT0 = (sel0 == 0 ? w00 : 0.0f) + (sel1 == 0 ? w01 : 0.0f);
    const float WT1 = (sel0 == 1 ? w00 : 0.0f) + (sel1 == 1 ? w01 : 0.0f);
    const float WB0 = (sel0 == 0 ? w10 : 0.0f) + (sel1 == 0 ? w11 : 0.0f);
    const float WB1 = (sel0 == 1 ? w10 : 0.0f) + (sel1 == 1 ? w11 : 0.0f);

    const int nb = b * (C_CONST * HW_CONST);
    off = make_int2(nb + y0c * W_CONST + xs,
                    nb + y1c * W_CONST + xs);
    w   = make_float4(WT0, WT1, WB0, WB1);
}

// grid = 8 XCDs x 8 c-groups x 64 roi-groups = 4096 blocks.
// blockIdx%8 = XCD (hardware round-robin); slot = blockIdx/8;
// c-group = slot/64 (slow), roi-group = slot%64 (fast) -> concurrent blocks
// on an XCD share one CPB-channel window (~2.5 MB, L2-resident).
__global__ __launch_bounds__(256) void roi_align_fused(
        const float* __restrict__ inp,
        const float* __restrict__ rois,
        float* __restrict__ out) {
    const int B   = blockIdx.x;
    const int xcd = B & 7;
    const int s   = B >> 3;            // 0..511
    const int cg  = s >> 6;            // 0..7  (slow)
    const int rg  = s & 63;            // 0..63 (fast)
    const int c0  = (xcd * 8 + cg) * CPB;   // XCD owns channels [xcd*32, xcd*32+32)
    const int m0  = rg * RPB;

    __shared__ int2   s_off[RPB * NPOS];   // 6.3 KB
    __shared__ float4 s_w[RPB * NPOS];     // 12.5 KB

    // ---- in-kernel table build: 784 entries over 256 threads (~3 passes) ----
    for (int e = threadIdx.x; e < RPB * NPOS; e += 256) {
        const int mloc = e / NPOS;
        const int pos  = e - mloc * NPOS;
        int2 off; float4 w;
        roi_entry(rois + (size_t)(m0 + mloc) * 5, pos, off, w);
        s_off[e] = off;
        s_w[e]   = w;
    }
    __syncthreads();

    const int lane = threadIdx.x & 63;
    const int wid  = threadIdx.x >> 6;      // 0..3, each wave: 4 ROIs
    if (lane >= NPOS) return;

#pragma unroll
    for (int i = 0; i < 4; ++i) {
        const int mloc = wid * 4 + i;
        const int t = mloc * NPOS + lane;
        const int2   off = s_off[t];
        const float4 w   = s_w[t];

        const float* pT = inp + (size_t)(unsigned)(off.x + c0 * HW_CONST);
        const float* pB = inp + (size_t)(unsigned)(off.y + c0 * HW_CONST);
        float* po = out + ((size_t)(m0 + mloc) * C_CONST + c0) * NPOS + lane;

#pragma unroll
        for (int c = 0; c < CPB; ++c) {
            float2 vT, vB;
            __builtin_memcpy(&vT, pT + (size_t)c * HW_CONST, 8);
            __builtin_memcpy(&vB, pB + (size_t)c * HW_CONST, 8);
            po[c * NPOS] = w.x * vT.x + w.y * vT.y + w.z * vB.x + w.w * vB.y;
        }
    }
}

// Fallback for unexpected M: position-resident single kernel (round-4 style).
__global__ __launch_bounds__(256) void roi_align_fallback(
        const float* __restrict__ inp,
        const float* __restrict__ rois,
        float* __restrict__ out) {
    const int m   = blockIdx.x >> 1;
    const int seg = blockIdx.x & 1;

    __shared__ int2   s_off[NPOS];
    __shared__ float4 s_w[NPOS];

    const float* __restrict__ r = rois + (size_t)m * 5;

    if (threadIdx.x < NPOS) {
        int2 off; float4 w;
        roi_entry(r, threadIdx.x, off, w);
        s_off[threadIdx.x] = off;
        s_w[threadIdx.x]   = w;
    }
    __syncthreads();

    const int lane = threadIdx.x & 63;
    const int wid  = threadIdx.x >> 6;
    if (lane < NPOS) {
        const int2   off = s_off[lane];
        const float4 w   = s_w[lane];
        const int c0 = seg * (C_CONST / 2) + wid;
        const float* pT = inp + (size_t)(unsigned)(off.x + c0 * HW_CONST);
        const float* pB = inp + (size_t)(unsigned)(off.y + c0 * HW_CONST);
        float* po = out + (size_t)m * (C_CONST * NPOS) + (size_t)c0 * NPOS + lane;
        const int cstep = 4 * HW_CONST;
#pragma unroll 8
        for (int k = 0; k < C_CONST / 2 / 4; ++k) {
            float2 vT, vB;
            __builtin_memcpy(&vT, pT, 8);
            __builtin_memcpy(&vB, pB, 8);
            *po = w.x * vT.x + w.y * vT.y + w.z * vB.x + w.w * vB.y;
            pT += cstep; pB += cstep;
            po += 4 * NPOS;
        }
    }
}

extern "C" void kernel_launch(void* const* d_in, const int* in_sizes, int n_in,
                              void* d_out, int out_size, void* d_ws, size_t ws_size,
                              hipStream_t stream) {
    const float* inp  = (const float*)d_in[0];
    const float* rois = (const float*)d_in[1];
    float* out = (float*)d_out;

    const int M = in_sizes[1] / 5;

    if (M == M_CONST) {
        const int grid = 8 * 8 * 64;          // 4096 blocks
        roi_align_fused<<<grid, 256, 0, stream>>>(inp, rois, out);
    } else {
        roi_align_fallback<<<M * 2, 256, 0, stream>>>(inp, rois, out);
    }
}